// Round 4
// baseline (290.875 us; speedup 1.0000x reference)
//
#include <hip/hip_runtime.h>

typedef unsigned short u16;
typedef unsigned int u32;
typedef short bf16x8 __attribute__((ext_vector_type(8)));
typedef float f32x4 __attribute__((ext_vector_type(4)));

#define BN 128

// ---------- helpers ----------
__device__ __forceinline__ u16 f2bf(float f) {
    u32 u = __float_as_uint(f);
    u32 r = (u + 0x7fffu + ((u >> 16) & 1u)) >> 16;   // RNE
    return (u16)r;
}

// async 16B/lane global->LDS (dest = wave-uniform base + lane*16)
__device__ __forceinline__ void gld_lds16(const void* g, void* s) {
    __builtin_amdgcn_global_load_lds(
        (__attribute__((address_space(1))) void*)(g),
        (__attribute__((address_space(3))) void*)(s),
        16, 0, 0);
}

// ---------- merged cast kernel: x (16M f32) + 4 weights (4M f32) -> bf16 ----------
__global__ void cast_all(const float* __restrict__ x,
                         const float* __restrict__ wq, const float* __restrict__ wk,
                         const float* __restrict__ wv, const float* __restrict__ wfc,
                         u16* __restrict__ xb, u16* __restrict__ wqkvb, u16* __restrict__ wfcb) {
    size_t g = (size_t)blockIdx.x * 256 + threadIdx.x;   // float4 index
    const float* s;
    u16* d;
    size_t off;
    if (g < 4194304u) {            // x: 16,777,216 floats = 4,194,304 float4
        s = x; d = xb; off = g;
    } else {
        size_t w = g - 4194304u;   // weights: 4 x 262,144 float4
        int y = (int)(w >> 18);
        off = w & 262143u;
        s = (y == 0) ? wq : (y == 1) ? wk : (y == 2) ? wv : wfc;
        d = (y < 3) ? (wqkvb + (size_t)y * 1048576u) : wfcb;
    }
    float4 v = ((const float4*)s)[off];
    ushort4 o;
    o.x = f2bf(v.x); o.y = f2bf(v.y); o.z = f2bf(v.z); o.w = f2bf(v.w);
    *(ushort4*)(d + off * 4) = o;
}

// ---------- bf16 GEMM (m97-structure, PROVEN 102us for GEMM1): C = A[M,K]*B[N,K]^T ----------
// MODE 0: u16 split store — col<2048 -> C0 (QK scratch, row stride 2048),
//         col>=2048 -> C1 (V buffer, row stride 1024). Block-uniform branch.
// MODE 1: fp32 store to C0, row stride N.
template <int BMT, int MODE>
__global__ __launch_bounds__(256, 2)
void gemm_bt(const u16* __restrict__ A, const u16* __restrict__ B,
             void* __restrict__ C0, void* __restrict__ C1, int M, int N, int K) {
    constexpr int WMT = BMT / 32;              // 16-row m-tiles per wave
    __shared__ __align__(16) u16 As[BMT * 64];
    __shared__ __align__(16) u16 Bs[BN * 64];

    const int tid  = threadIdx.x;
    const int lane = tid & 63;
    const int wave = tid >> 6;
    const int wm = wave >> 1, wn = wave & 1;
    const int bm = blockIdx.y * BMT;
    const int bn = blockIdx.x * BN;

    const int srow   = lane >> 3;            // row within 8-row staging group
    const int schunk = (lane & 7) ^ srow;    // xor-swizzled source chunk

    f32x4 acc[WMT][4];
#pragma unroll
    for (int i = 0; i < WMT; ++i)
#pragma unroll
        for (int j = 0; j < 4; ++j) acc[i][j] = (f32x4){0.f, 0.f, 0.f, 0.f};

    const int nkt = K >> 6;
    for (int kt = 0; kt < nkt; ++kt) {
        const int k0 = kt << 6;
        __syncthreads();   // prior compute done reading LDS
#pragma unroll
        for (int j = 0; j < WMT; ++j) {      // A: BMT rows, 32 rows/round
            const int r = j * 32 + wave * 8;
            gld_lds16(A + (size_t)(bm + r + srow) * K + k0 + schunk * 8, &As[r * 64]);
        }
#pragma unroll
        for (int j = 0; j < 4; ++j) {        // B: 128 rows
            const int r = j * 32 + wave * 8;
            gld_lds16(B + (size_t)(bn + r + srow) * K + k0 + schunk * 8, &Bs[r * 64]);
        }
        __syncthreads();   // compiler drains vmcnt before barrier
#pragma unroll
        for (int kk = 0; kk < 2; ++kk) {
            const int c = kk * 4 + (lane >> 4);
            bf16x8 af[WMT], bfr[4];
#pragma unroll
            for (int i = 0; i < WMT; ++i) {
                int m = wm * (WMT * 16) + i * 16 + (lane & 15);
                af[i] = *(const bf16x8*)&As[m * 64 + ((c ^ (m & 7)) << 3)];
            }
#pragma unroll
            for (int j = 0; j < 4; ++j) {
                int n = wn * 64 + j * 16 + (lane & 15);
                bfr[j] = *(const bf16x8*)&Bs[n * 64 + ((c ^ (n & 7)) << 3)];
            }
#pragma unroll
            for (int i = 0; i < WMT; ++i)
#pragma unroll
                for (int j = 0; j < 4; ++j)
                    acc[i][j] = __builtin_amdgcn_mfma_f32_16x16x32_bf16(
                        af[i], bfr[j], acc[i][j], 0, 0, 0);
        }
    }

    // epilogue: D layout col=lane&15, row=(lane>>4)*4+reg
    const int cr = (lane >> 4) * 4;
    const int cc = lane & 15;
#pragma unroll
    for (int i = 0; i < WMT; ++i) {
#pragma unroll
        for (int j = 0; j < 4; ++j) {
            const int row0 = bm + wm * (WMT * 16) + i * 16 + cr;
            const int col  = bn + wn * 64 + j * 16 + cc;
#pragma unroll
            for (int r = 0; r < 4; ++r) {
                float v = acc[i][j][r];
                const int row = row0 + r;
                if (MODE == 0) {
                    if (col < 2048)
                        ((u16*)C0)[(size_t)row * 2048 + col] = f2bf(v);
                    else
                        ((u16*)C1)[(size_t)row * 1024 + (col - 2048)] = f2bf(v);
                } else {
                    ((float*)C0)[(size_t)row * N + col] = v;
                }
            }
        }
    }
}

// ---------- 256x256 deep-pipelined bf16 GEMM (kept for GEMM2 only) ----------
// Round-1 data: GEMM1 regressed here (lockstep barriers at 1 blk/CU), but
// total-time accounting attributed ~20us gain to GEMM2 -> keep for GEMM2 only.
template <int MODE>
__global__ __launch_bounds__(512, 2)
void gemm_bt8(const u16* __restrict__ A, const u16* __restrict__ B,
              void* __restrict__ C0, void* __restrict__ C1,
              int M, int N, int K) {
    __shared__ __align__(16) u16 sA[4][8192];   // 4 x 256x32 bf16 = 64 KiB
    __shared__ __align__(16) u16 sB[4][8192];   // 64 KiB

    const int tid  = threadIdx.x;
    const int lane = tid & 63;
    const int wave = tid >> 6;
    const int wm = wave >> 2;          // 0..1  (M half)
    const int wn = wave & 3;           // 0..3  (N quarter)

    // bijective XCD-aware block swizzle (nwg % 8 == 0)
    const int ntx = N >> 8;
    const int cpx = gridDim.x >> 3;
    const int swz = ((int)blockIdx.x & 7) * cpx + ((int)blockIdx.x >> 3);
    const int bm = (swz / ntx) << 8;
    const int bn = (swz % ntx) << 8;

    // ---- staging coords: one call = 512 thr x 16B = 128 rows x 64B ----
    const int srow = tid >> 2;                           // row within 128-half
    const int sch  = (tid & 3) ^ ((srow >> 1) & 3);      // pre-swizzled src chunk
    const u16* a0 = A + (size_t)(bm +       srow) * K + sch * 8;
    const u16* a1 = A + (size_t)(bm + 128 + srow) * K + sch * 8;
    const u16* b0 = B + (size_t)(bn +       srow) * K + sch * 8;
    const u16* b1 = B + (size_t)(bn + 128 + srow) * K + sch * 8;
    const int ldst = tid * 8;                            // linear LDS dest (u16)

    auto stA = [&](int t) {
        u16* d = &sA[t & 3][0];
        gld_lds16(a0 + t * 32, d + ldst);
        gld_lds16(a1 + t * 32, d + 4096 + ldst);
    };
    auto stB = [&](int t) {
        u16* d = &sB[t & 3][0];
        gld_lds16(b0 + t * 32, d + ldst);
        gld_lds16(b1 + t * 32, d + 4096 + ldst);
    };

    // ---- fragment read coords (per-lane constants) ----
    const int l15 = lane & 15;
    const int sc8 = (((lane >> 4) ^ ((l15 >> 1) & 3)) << 3);  // swizzled k-chunk (u16)
    const int arow = wm * 128 + l15;    // + mt*16
    const int brow = wn * 64  + l15;    // + nt*16

    f32x4 acc[8][4];
#pragma unroll
    for (int i = 0; i < 8; ++i)
#pragma unroll
        for (int j = 0; j < 4; ++j) acc[i][j] = (f32x4){0.f, 0.f, 0.f, 0.f};

    const int T = K >> 5;   // K-tiles of 32

    stA(0); stB(0); stA(1); stB(1); stA(2); stB(2);
    asm volatile("s_waitcnt vmcnt(8)" ::: "memory");
    asm volatile("s_barrier" ::: "memory");

    for (int w = 0; w < T; ++w) {
        const u16* pa = &sA[w & 3][0];
        const u16* pb = &sB[w & 3][0];

        bf16x8 af[4], bf[4];
#pragma unroll
        for (int i = 0; i < 4; ++i)
            af[i] = *(const bf16x8*)&pa[(arow + i * 16) * 32 + sc8];
#pragma unroll
        for (int j = 0; j < 4; ++j)
            bf[j] = *(const bf16x8*)&pb[(brow + j * 16) * 32 + sc8];
        if (w + 3 < T) stA(w + 3);
        asm volatile("s_barrier" ::: "memory");
        asm volatile("s_waitcnt lgkmcnt(0)" ::: "memory");
        __builtin_amdgcn_s_setprio(1);
#pragma unroll
        for (int i = 0; i < 4; ++i)
#pragma unroll
            for (int j = 0; j < 4; ++j)
                acc[i][j] = __builtin_amdgcn_mfma_f32_16x16x32_bf16(
                    af[i], bf[j], acc[i][j], 0, 0, 0);
        __builtin_amdgcn_s_setprio(0);
        asm volatile("s_barrier" ::: "memory");

        bf16x8 ag[4];
#pragma unroll
        for (int i = 0; i < 4; ++i)
            ag[i] = *(const bf16x8*)&pa[(arow + (i + 4) * 16) * 32 + sc8];
        if (w + 3 < T) stB(w + 3);
        if (w < T - 3)       asm volatile("s_waitcnt vmcnt(8)" ::: "memory");
        else if (w == T - 3) asm volatile("s_waitcnt vmcnt(4)" ::: "memory");
        else if (w == T - 2) asm volatile("s_waitcnt vmcnt(0)" ::: "memory");
        asm volatile("s_barrier" ::: "memory");
        asm volatile("s_waitcnt lgkmcnt(0)" ::: "memory");
        __builtin_amdgcn_s_setprio(1);
#pragma unroll
        for (int i = 0; i < 4; ++i)
#pragma unroll
            for (int j = 0; j < 4; ++j)
                acc[i + 4][j] = __builtin_amdgcn_mfma_f32_16x16x32_bf16(
                    ag[i], bf[j], acc[i + 4][j], 0, 0, 0);
        __builtin_amdgcn_s_setprio(0);
        asm volatile("s_barrier" ::: "memory");
    }

    const int cr = (lane >> 4) * 4;
    const int cc = l15;
#pragma unroll
    for (int i = 0; i < 8; ++i) {
#pragma unroll
        for (int j = 0; j < 4; ++j) {
            const int row0 = bm + wm * 128 + i * 16 + cr;
            const int col  = bn + wn * 64 + j * 16 + cc;
#pragma unroll
            for (int r = 0; r < 4; ++r) {
                float v = acc[i][j][r];
                const int row = row0 + r;
                if (MODE == 0) {
                    if (col < 2048)
                        ((u16*)C0)[(size_t)row * 2048 + col] = f2bf(v);
                    else
                        ((u16*)C1)[(size_t)row * 1024 + (col - 2048)] = f2bf(v);
                } else {
                    ((float*)C0)[(size_t)row * N + col] = v;
                }
            }
        }
    }
}

// ---------- per-token attention v4: async-staged QK + barrier-free ----------
// Per wave = 1 token; all LDS producer->consumer pairs are SAME-WAVE, so
// __syncthreads is replaced by per-wave s_waitcnt (no inter-wave sync at all).
//  * Q,K staged via global_load_lds (4 async 16B/lane calls, no reg round-trip),
//    source pre-swizzled with the involution chunk^((chunk>>3)&7) (T21: linear
//    dest + inverse-swz source + swz read). Frag reads use pos = row*8 +
//    (chunk ^ (row&7)) — the same XOR family as gemm_bt (measured 0 conflicts).
//    [r3 post-mortem: direct-global frag loads cost ~+15us from 4x L2-request
//     amplification (16 scattered 64B txns/load); staged+coalesced is the fix.]
//  * V transpose scatter, softmax, PV: verbatim proven path.
//  * O bounced via padded LDS [16][72] aliased into the dead sQK region
//    (QK reads complete before the lgkmcnt(0) that precedes sO writes) ->
//    LDS 26KB/block -> 6 blocks/CU.
__global__ __launch_bounds__(256)
void attn_kernel(const u16* __restrict__ QK, const u16* __restrict__ V,
                 u16* __restrict__ O) {
    __shared__ __align__(16) u16 sQK[4][2048];  // Q[16][64] | K[16][64], chunk-swizzled
    __shared__ __align__(16) u16 sV[4][1024];   // V^T: [d][t], blk swizzle (proven)
    __shared__ __align__(16) u16 sP[4][256];    // P[h][t] bf16

    const int lane = threadIdx.x & 63;
    const int wave = threadIdx.x >> 6;
    const size_t m = (size_t)blockIdx.x * 4 + wave;
    const u16* bqk = QK + m * 2048;
    const u16* bv  = V + m * 1024;

    // ---- stage Q,K async: LDS 16B-chunk position p holds global chunk
    //      (p&~7) | ((p&7) ^ ((p>>3)&7))  (involution, bijective per row) ----
#pragma unroll
    for (int j = 0; j < 4; ++j) {
        int p = j * 64 + lane;
        int src = (p & ~7) | ((p & 7) ^ ((p >> 3) & 7));
        gld_lds16(bqk + src * 8, &sQK[wave][p * 8]);
    }

    // ---- stage V transposed: (t,d) -> sV[d*16 + blk*8 + (t&7)],
    //      blk = (t>>3) ^ ((d>>3)&1)  [proven path] ----
#pragma unroll
    for (int c6 = 0; c6 < 2; ++c6) {
        int cc = c6 * 64 + lane;             // 0..127
        int t = cc >> 3, d0 = (cc & 7) * 8;
        uint4 v = *(const uint4*)(bv + cc * 8);
        u16 e[8]; *(uint4*)e = v;
#pragma unroll
        for (int k = 0; k < 8; ++k) {
            int d = d0 + k;
            int blk = (t >> 3) ^ ((d >> 3) & 1);
            sV[wave][d * 16 + blk * 8 + (t & 7)] = e[k];
        }
    }

    const int ln = lane & 15;
    const int g  = lane >> 4;

    // QK landed in LDS (same-wave; also covers the V uint4 loads)
    asm volatile("s_waitcnt vmcnt(0)" ::: "memory");

    // ---- S^T = K·Q^T from swizzled LDS ----
    // chunk c of row ln sits at position ln*8 + (c ^ (ln&7)); K rows at +128.
    const int sel0 = (g       ^ (ln & 7));
    const int sel1 = ((g + 4) ^ (ln & 7));
    f32x4 s = (f32x4){0.f, 0.f, 0.f, 0.f};
    {
        bf16x8 a0 = *(const bf16x8*)&sQK[wave][(128 + ln * 8 + sel0) * 8];  // K, k-lo
        bf16x8 b0 = *(const bf16x8*)&sQK[wave][(      ln * 8 + sel0) * 8];  // Q, k-lo
        s = __builtin_amdgcn_mfma_f32_16x16x32_bf16(a0, b0, s, 0, 0, 0);
        bf16x8 a1 = *(const bf16x8*)&sQK[wave][(128 + ln * 8 + sel1) * 8];  // K, k-hi
        bf16x8 b1 = *(const bf16x8*)&sQK[wave][(      ln * 8 + sel1) * 8];  // Q, k-hi
        s = __builtin_amdgcn_mfma_f32_16x16x32_bf16(a1, b1, s, 0, 0, 0);
    }
    float sv[4];
#pragma unroll
    for (int r = 0; r < 4; ++r) sv[r] = s[r] * 0.125f;

    // ---- softmax over t (lane holds S^T[t=g*4+r][h=ln]) ----
    float mx = fmaxf(fmaxf(sv[0], sv[1]), fmaxf(sv[2], sv[3]));
    mx = fmaxf(mx, __shfl_xor(mx, 16));
    mx = fmaxf(mx, __shfl_xor(mx, 32));
    float e[4], sum = 0.f;
#pragma unroll
    for (int r = 0; r < 4; ++r) { e[r] = __expf(sv[r] - mx); sum += e[r]; }
    sum += __shfl_xor(sum, 16);
    sum += __shfl_xor(sum, 32);
    const float inv = 1.f / sum;

    // ---- P[h][t] -> LDS bf16 (row-major [16][16]) ----
    ushort4 pb;
    pb.x = f2bf(e[0] * inv); pb.y = f2bf(e[1] * inv);
    pb.z = f2bf(e[2] * inv); pb.w = f2bf(e[3] * inv);
    *(ushort4*)&sP[wave][ln * 16 + g * 4] = pb;
    // drains ALL prior ds ops (incl. QK frag reads + V scatter + P write):
    // after this, sQK region is dead -> safe to alias as sO.
    asm volatile("s_waitcnt lgkmcnt(0)" ::: "memory");

    u16* sO = &sQK[wave][0];   // O bounce [16][72], aliases dead QK tile

    // ---- O^T = V^T·P^T (zero-padded k), proven path ----
    bf16x8 bl = *(const bf16x8*)&sP[wave][ln * 16 + (g & 1) * 8];
    bf16x8 bz = (bf16x8){0, 0, 0, 0, 0, 0, 0, 0};
    bf16x8 bp = (g < 2) ? bl : bz;

#pragma unroll
    for (int dt = 0; dt < 4; ++dt) {
        int d = dt * 16 + ln;
        int blk = (g & 1) ^ ((d >> 3) & 1);
        bf16x8 av = *(const bf16x8*)&sV[wave][d * 16 + blk * 8];
        f32x4 o = __builtin_amdgcn_mfma_f32_16x16x32_bf16(
            av, bp, (f32x4){0.f, 0.f, 0.f, 0.f}, 0, 0, 0);
        // o[r] = O^T[d = dt*16 + g*4 + r][h = ln] -> sO[h][d], 4 contiguous
        ushort4 ob;
        ob.x = f2bf(o[0]); ob.y = f2bf(o[1]);
        ob.z = f2bf(o[2]); ob.w = f2bf(o[3]);
        *(ushort4*)&sO[ln * 72 + dt * 16 + g * 4] = ob;
    }
    asm volatile("s_waitcnt lgkmcnt(0)" ::: "memory");   // sO writes done (same wave)

    // ---- coalesced store: 2 x uint4 per lane ----
#pragma unroll
    for (int c6 = 0; c6 < 2; ++c6) {
        int c = c6 * 64 + lane;              // chunk 0..127 of 8 u16
        uint4 v = *(const uint4*)&sO[(c >> 3) * 72 + (c & 7) * 8];
        *(uint4*)(O + m * 1024 + c * 8) = v;
    }
}

// ---------- launch ----------
extern "C" void kernel_launch(void* const* d_in, const int* in_sizes, int n_in,
                              void* d_out, int out_size, void* d_ws, size_t ws_size,
                              hipStream_t stream) {
    const float* x   = (const float*)d_in[0];
    const float* Wq  = (const float*)d_in[1];
    const float* Wk  = (const float*)d_in[2];
    const float* Wv  = (const float*)d_in[3];
    const float* Wfc = (const float*)d_in[4];

    // B=4, S=4096, DM=1024 -> M=16384, K=1024, Nqkv=3072
    const int M = 16384, K = 1024, NQKV = 3072, N2 = 1024;

    // ws: 72 MB. Q||K scratch lives in d_out (u16), overwritten by
    // GEMM2's final fp32 store after attn consumed it (stream-ordered).
    char* ws = (char*)d_ws;
    u16* xb    = (u16*)ws;                                  // 33,554,432 B (also O later)
    u16* wqkvb = (u16*)(ws + 33554432);                     //  6,291,456 B
    u16* wfcb  = (u16*)(ws + 33554432 + 6291456);           //  2,097,152 B
    u16* vbuf  = (u16*)(ws + 33554432 + 6291456 + 2097152); // 33,554,432 B
    u16* qkbuf = (u16*)d_out;                               // 64 MB scratch

    cast_all<<<20480, 256, 0, stream>>>(x, Wq, Wk, Wv, Wfc, xb, wqkvb, wfcb);

    // GEMM1: proven 128-tile structure (102us, MfmaUtil 46%)
    gemm_bt<128, 0><<<dim3(NQKV / BN, M / 128), 256, 0, stream>>>(
        xb, wqkvb, qkbuf, vbuf, M, NQKV, K);

    u16* Ob = xb;   // alias: GEMM1 was the last reader of xb
    attn_kernel<<<M / 4, 256, 0, stream>>>(qkbuf, vbuf, Ob);

    // GEMM2: deep-pipelined 256^2 (256 blocks, %8==0)
    gemm_bt8<1><<<256, 512, 0, stream>>>(Ob, wfcb, d_out, nullptr, M, N2, K);
}

// Round 5
// 281.845 us; speedup vs baseline: 1.0320x; 1.0320x over previous
//
#include <hip/hip_runtime.h>

typedef unsigned short u16;
typedef unsigned int u32;
typedef short bf16x8 __attribute__((ext_vector_type(8)));
typedef float f32x4 __attribute__((ext_vector_type(4)));

#define BN 128

// ---------- helpers ----------
__device__ __forceinline__ u16 f2bf(float f) {
    u32 u = __float_as_uint(f);
    u32 r = (u + 0x7fffu + ((u >> 16) & 1u)) >> 16;   // RNE
    return (u16)r;
}

// async 16B/lane global->LDS (dest = wave-uniform base + lane*16)
__device__ __forceinline__ void gld_lds16(const void* g, void* s) {
    __builtin_amdgcn_global_load_lds(
        (__attribute__((address_space(1))) void*)(g),
        (__attribute__((address_space(3))) void*)(s),
        16, 0, 0);
}

// ---------- merged cast kernel: x (16M f32) + 4 weights (4M f32) -> bf16 ----------
__global__ void cast_all(const float* __restrict__ x,
                         const float* __restrict__ wq, const float* __restrict__ wk,
                         const float* __restrict__ wv, const float* __restrict__ wfc,
                         u16* __restrict__ xb, u16* __restrict__ wqkvb, u16* __restrict__ wfcb) {
    size_t g = (size_t)blockIdx.x * 256 + threadIdx.x;   // float4 index
    const float* s;
    u16* d;
    size_t off;
    if (g < 4194304u) {            // x: 16,777,216 floats = 4,194,304 float4
        s = x; d = xb; off = g;
    } else {
        size_t w = g - 4194304u;   // weights: 4 x 262,144 float4
        int y = (int)(w >> 18);
        off = w & 262143u;
        s = (y == 0) ? wq : (y == 1) ? wk : (y == 2) ? wv : wfc;
        d = (y < 3) ? (wqkvb + (size_t)y * 1048576u) : wfcb;
    }
    float4 v = ((const float4*)s)[off];
    ushort4 o;
    o.x = f2bf(v.x); o.y = f2bf(v.y); o.z = f2bf(v.z); o.w = f2bf(v.w);
    *(ushort4*)(d + off * 4) = o;
}

// ---------- bf16 GEMM (m97-structure, PROVEN ~102-105us for GEMM1) ----------
// MODE 0: u16 split store — col<2048 -> C0 (QK scratch, row stride 2048),
//         col>=2048 -> C1 (V buffer, row stride 1024). Block-uniform branch.
// MODE 1: fp32 store to C0, row stride N.
template <int BMT, int MODE>
__global__ __launch_bounds__(256, 2)
void gemm_bt(const u16* __restrict__ A, const u16* __restrict__ B,
             void* __restrict__ C0, void* __restrict__ C1, int M, int N, int K) {
    constexpr int WMT = BMT / 32;              // 16-row m-tiles per wave
    __shared__ __align__(16) u16 As[BMT * 64];
    __shared__ __align__(16) u16 Bs[BN * 64];

    const int tid  = threadIdx.x;
    const int lane = tid & 63;
    const int wave = tid >> 6;
    const int wm = wave >> 1, wn = wave & 1;
    const int bm = blockIdx.y * BMT;
    const int bn = blockIdx.x * BN;

    const int srow   = lane >> 3;            // row within 8-row staging group
    const int schunk = (lane & 7) ^ srow;    // xor-swizzled source chunk

    f32x4 acc[WMT][4];
#pragma unroll
    for (int i = 0; i < WMT; ++i)
#pragma unroll
        for (int j = 0; j < 4; ++j) acc[i][j] = (f32x4){0.f, 0.f, 0.f, 0.f};

    const int nkt = K >> 6;
    for (int kt = 0; kt < nkt; ++kt) {
        const int k0 = kt << 6;
        __syncthreads();   // prior compute done reading LDS
#pragma unroll
        for (int j = 0; j < WMT; ++j) {      // A: BMT rows, 32 rows/round
            const int r = j * 32 + wave * 8;
            gld_lds16(A + (size_t)(bm + r + srow) * K + k0 + schunk * 8, &As[r * 64]);
        }
#pragma unroll
        for (int j = 0; j < 4; ++j) {        // B: 128 rows
            const int r = j * 32 + wave * 8;
            gld_lds16(B + (size_t)(bn + r + srow) * K + k0 + schunk * 8, &Bs[r * 64]);
        }
        __syncthreads();   // compiler drains vmcnt before barrier
#pragma unroll
        for (int kk = 0; kk < 2; ++kk) {
            const int c = kk * 4 + (lane >> 4);
            bf16x8 af[WMT], bfr[4];
#pragma unroll
            for (int i = 0; i < WMT; ++i) {
                int m = wm * (WMT * 16) + i * 16 + (lane & 15);
                af[i] = *(const bf16x8*)&As[m * 64 + ((c ^ (m & 7)) << 3)];
            }
#pragma unroll
            for (int j = 0; j < 4; ++j) {
                int n = wn * 64 + j * 16 + (lane & 15);
                bfr[j] = *(const bf16x8*)&Bs[n * 64 + ((c ^ (n & 7)) << 3)];
            }
#pragma unroll
            for (int i = 0; i < WMT; ++i)
#pragma unroll
                for (int j = 0; j < 4; ++j)
                    acc[i][j] = __builtin_amdgcn_mfma_f32_16x16x32_bf16(
                        af[i], bfr[j], acc[i][j], 0, 0, 0);
        }
    }

    // epilogue: D layout col=lane&15, row=(lane>>4)*4+reg
    const int cr = (lane >> 4) * 4;
    const int cc = lane & 15;
#pragma unroll
    for (int i = 0; i < WMT; ++i) {
#pragma unroll
        for (int j = 0; j < 4; ++j) {
            const int row0 = bm + wm * (WMT * 16) + i * 16 + cr;
            const int col  = bn + wn * 64 + j * 16 + cc;
#pragma unroll
            for (int r = 0; r < 4; ++r) {
                float v = acc[i][j][r];
                const int row = row0 + r;
                if (MODE == 0) {
                    if (col < 2048)
                        ((u16*)C0)[(size_t)row * 2048 + col] = f2bf(v);
                    else
                        ((u16*)C1)[(size_t)row * 1024 + (col - 2048)] = f2bf(v);
                } else {
                    ((float*)C0)[(size_t)row * N + col] = v;
                }
            }
        }
    }
}

// ---------- 256x256 deep-pipelined bf16 GEMM (kept for GEMM2 only) ----------
// r0->r1 ledger: -20.6us vs gemm_bt<256,1> on GEMM2 (attn held fixed).
template <int MODE>
__global__ __launch_bounds__(512, 2)
void gemm_bt8(const u16* __restrict__ A, const u16* __restrict__ B,
              void* __restrict__ C0, void* __restrict__ C1,
              int M, int N, int K) {
    __shared__ __align__(16) u16 sA[4][8192];   // 4 x 256x32 bf16 = 64 KiB
    __shared__ __align__(16) u16 sB[4][8192];   // 64 KiB

    const int tid  = threadIdx.x;
    const int lane = tid & 63;
    const int wave = tid >> 6;
    const int wm = wave >> 2;          // 0..1  (M half)
    const int wn = wave & 3;           // 0..3  (N quarter)

    // bijective XCD-aware block swizzle (nwg % 8 == 0)
    const int ntx = N >> 8;
    const int cpx = gridDim.x >> 3;
    const int swz = ((int)blockIdx.x & 7) * cpx + ((int)blockIdx.x >> 3);
    const int bm = (swz / ntx) << 8;
    const int bn = (swz % ntx) << 8;

    // ---- staging coords: one call = 512 thr x 16B = 128 rows x 64B ----
    const int srow = tid >> 2;                           // row within 128-half
    const int sch  = (tid & 3) ^ ((srow >> 1) & 3);      // pre-swizzled src chunk
    const u16* a0 = A + (size_t)(bm +       srow) * K + sch * 8;
    const u16* a1 = A + (size_t)(bm + 128 + srow) * K + sch * 8;
    const u16* b0 = B + (size_t)(bn +       srow) * K + sch * 8;
    const u16* b1 = B + (size_t)(bn + 128 + srow) * K + sch * 8;
    const int ldst = tid * 8;                            // linear LDS dest (u16)

    auto stA = [&](int t) {
        u16* d = &sA[t & 3][0];
        gld_lds16(a0 + t * 32, d + ldst);
        gld_lds16(a1 + t * 32, d + 4096 + ldst);
    };
    auto stB = [&](int t) {
        u16* d = &sB[t & 3][0];
        gld_lds16(b0 + t * 32, d + ldst);
        gld_lds16(b1 + t * 32, d + 4096 + ldst);
    };

    // ---- fragment read coords (per-lane constants) ----
    const int l15 = lane & 15;
    const int sc8 = (((lane >> 4) ^ ((l15 >> 1) & 3)) << 3);  // swizzled k-chunk (u16)
    const int arow = wm * 128 + l15;    // + mt*16
    const int brow = wn * 64  + l15;    // + nt*16

    f32x4 acc[8][4];
#pragma unroll
    for (int i = 0; i < 8; ++i)
#pragma unroll
        for (int j = 0; j < 4; ++j) acc[i][j] = (f32x4){0.f, 0.f, 0.f, 0.f};

    const int T = K >> 5;   // K-tiles of 32

    stA(0); stB(0); stA(1); stB(1); stA(2); stB(2);
    asm volatile("s_waitcnt vmcnt(8)" ::: "memory");
    asm volatile("s_barrier" ::: "memory");

    for (int w = 0; w < T; ++w) {
        const u16* pa = &sA[w & 3][0];
        const u16* pb = &sB[w & 3][0];

        bf16x8 af[4], bf[4];
#pragma unroll
        for (int i = 0; i < 4; ++i)
            af[i] = *(const bf16x8*)&pa[(arow + i * 16) * 32 + sc8];
#pragma unroll
        for (int j = 0; j < 4; ++j)
            bf[j] = *(const bf16x8*)&pb[(brow + j * 16) * 32 + sc8];
        if (w + 3 < T) stA(w + 3);
        asm volatile("s_barrier" ::: "memory");
        asm volatile("s_waitcnt lgkmcnt(0)" ::: "memory");
        __builtin_amdgcn_s_setprio(1);
#pragma unroll
        for (int i = 0; i < 4; ++i)
#pragma unroll
            for (int j = 0; j < 4; ++j)
                acc[i][j] = __builtin_amdgcn_mfma_f32_16x16x32_bf16(
                    af[i], bf[j], acc[i][j], 0, 0, 0);
        __builtin_amdgcn_s_setprio(0);
        asm volatile("s_barrier" ::: "memory");

        bf16x8 ag[4];
#pragma unroll
        for (int i = 0; i < 4; ++i)
            ag[i] = *(const bf16x8*)&pa[(arow + (i + 4) * 16) * 32 + sc8];
        if (w + 3 < T) stB(w + 3);
        if (w < T - 3)       asm volatile("s_waitcnt vmcnt(8)" ::: "memory");
        else if (w == T - 3) asm volatile("s_waitcnt vmcnt(4)" ::: "memory");
        else if (w == T - 2) asm volatile("s_waitcnt vmcnt(0)" ::: "memory");
        asm volatile("s_barrier" ::: "memory");
        asm volatile("s_waitcnt lgkmcnt(0)" ::: "memory");
        __builtin_amdgcn_s_setprio(1);
#pragma unroll
        for (int i = 0; i < 4; ++i)
#pragma unroll
            for (int j = 0; j < 4; ++j)
                acc[i + 4][j] = __builtin_amdgcn_mfma_f32_16x16x32_bf16(
                    ag[i], bf[j], acc[i + 4][j], 0, 0, 0);
        __builtin_amdgcn_s_setprio(0);
        asm volatile("s_barrier" ::: "memory");
    }

    const int cr = (lane >> 4) * 4;
    const int cc = l15;
#pragma unroll
    for (int i = 0; i < 8; ++i) {
#pragma unroll
        for (int j = 0; j < 4; ++j) {
            const int row0 = bm + wm * 128 + i * 16 + cr;
            const int col  = bn + wn * 64 + j * 16 + cc;
#pragma unroll
            for (int r = 0; r < 4; ++r) {
                float v = acc[i][j][r];
                const int row = row0 + r;
                if (MODE == 0) {
                    if (col < 2048)
                        ((u16*)C0)[(size_t)row * 2048 + col] = f2bf(v);
                    else
                        ((u16*)C1)[(size_t)row * 1024 + (col - 2048)] = f2bf(v);
                } else {
                    ((float*)C0)[(size_t)row * N + col] = v;
                }
            }
        }
    }
}

// ---------- per-token attention (v1 VERBATIM — fastest measured variant) ----------
// r3 (direct-global QK + sO bounce): +15.7us. r4 (staged QK + sO bounce): +17.6us.
// The bounce's serial LDS round-trip + lgkm waits on the wave critical path is
// the prime suspect; v1's 8B direct stores are fire-and-forget (latency-hidden).
// QK row m: [q(1024) | k(1024)] bf16 (in d_out scratch), V row m: [v(1024)].
// S^T = K·Q^T (two 16x16x32 MFMAs), softmax over t, O^T = V^T·P^T.
__global__ __launch_bounds__(256)
void attn_kernel(const u16* __restrict__ QK, const u16* __restrict__ V,
                 u16* __restrict__ O) {
    __shared__ __align__(16) u16 sQ[4][16 * 80];   // rows padded 64->80
    __shared__ __align__(16) u16 sK[4][16 * 80];
    __shared__ __align__(16) u16 sV[4][64 * 16];   // V^T: [d][t], blk swizzle
    __shared__ __align__(16) u16 sP[4][16 * 16];   // P[h][t] bf16

    const int lane = threadIdx.x & 63;
    const int wave = threadIdx.x >> 6;
    const size_t m = (size_t)blockIdx.x * 4 + wave;
    const u16* bqk = QK + m * 2048;
    const u16* bv  = V + m * 1024;

    // ---- stage Q,K: 256 chunks of 8 elems -> [row][80] b128 writes ----
#pragma unroll
    for (int c6 = 0; c6 < 4; ++c6) {
        int chunk = c6 * 64 + lane;          // 0..255
        uint4 v = *(const uint4*)(bqk + chunk * 8);
        int cc = chunk & 127;
        int row = cc >> 3, pch = cc & 7;
        u16* dst = (chunk < 128) ? sQ[wave] : sK[wave];
        *(uint4*)&dst[row * 80 + pch * 8] = v;
    }
    // ---- stage V transposed: (t,d) -> sV[d*16 + blk*8 + (t&7)],
    //      blk = (t>>3) ^ ((d>>3)&1) ----
#pragma unroll
    for (int c6 = 0; c6 < 2; ++c6) {
        int cc = c6 * 64 + lane;             // 0..127
        int t = cc >> 3, d0 = (cc & 7) * 8;
        uint4 v = *(const uint4*)(bv + cc * 8);
        u16 e[8]; *(uint4*)e = v;
#pragma unroll
        for (int k = 0; k < 8; ++k) {
            int d = d0 + k;
            int blk = (t >> 3) ^ ((d >> 3) & 1);
            sV[wave][d * 16 + blk * 8 + (t & 7)] = e[k];
        }
    }
    __syncthreads();

    const int ln = lane & 15;
    const int g  = lane >> 4;

    // ---- S^T = K·Q^T ----
    f32x4 s = (f32x4){0.f, 0.f, 0.f, 0.f};
    {
        bf16x8 a0 = *(const bf16x8*)&sK[wave][ln * 80 + g * 8];
        bf16x8 b0 = *(const bf16x8*)&sQ[wave][ln * 80 + g * 8];
        s = __builtin_amdgcn_mfma_f32_16x16x32_bf16(a0, b0, s, 0, 0, 0);
        bf16x8 a1 = *(const bf16x8*)&sK[wave][ln * 80 + 32 + g * 8];
        bf16x8 b1 = *(const bf16x8*)&sQ[wave][ln * 80 + 32 + g * 8];
        s = __builtin_amdgcn_mfma_f32_16x16x32_bf16(a1, b1, s, 0, 0, 0);
    }
    float sv[4];
#pragma unroll
    for (int r = 0; r < 4; ++r) sv[r] = s[r] * 0.125f;

    // ---- softmax over t ----
    float mx = fmaxf(fmaxf(sv[0], sv[1]), fmaxf(sv[2], sv[3]));
    mx = fmaxf(mx, __shfl_xor(mx, 16));
    mx = fmaxf(mx, __shfl_xor(mx, 32));
    float e[4], sum = 0.f;
#pragma unroll
    for (int r = 0; r < 4; ++r) { e[r] = __expf(sv[r] - mx); sum += e[r]; }
    sum += __shfl_xor(sum, 16);
    sum += __shfl_xor(sum, 32);
    const float inv = 1.f / sum;

    // ---- P[h][t] -> LDS bf16 ----
    ushort4 pb;
    pb.x = f2bf(e[0] * inv); pb.y = f2bf(e[1] * inv);
    pb.z = f2bf(e[2] * inv); pb.w = f2bf(e[3] * inv);
    *(ushort4*)&sP[wave][ln * 16 + g * 4] = pb;
    __syncthreads();

    // ---- O^T = V^T·P^T (zero-padded k) ----
    bf16x8 bl = *(const bf16x8*)&sP[wave][ln * 16 + (g & 1) * 8];
    bf16x8 bz = (bf16x8){0, 0, 0, 0, 0, 0, 0, 0};
    bf16x8 bp = (g < 2) ? bl : bz;

#pragma unroll
    for (int dt = 0; dt < 4; ++dt) {
        int d = dt * 16 + ln;
        int blk = (g & 1) ^ ((d >> 3) & 1);
        bf16x8 av = *(const bf16x8*)&sV[wave][d * 16 + blk * 8];
        f32x4 o = __builtin_amdgcn_mfma_f32_16x16x32_bf16(
            av, bp, (f32x4){0.f, 0.f, 0.f, 0.f}, 0, 0, 0);
        ushort4 ob;
        ob.x = f2bf(o[0]); ob.y = f2bf(o[1]);
        ob.z = f2bf(o[2]); ob.w = f2bf(o[3]);
        *(ushort4*)(O + m * 1024 + ln * 64 + dt * 16 + g * 4) = ob;
    }
}

// ---------- launch ----------
extern "C" void kernel_launch(void* const* d_in, const int* in_sizes, int n_in,
                              void* d_out, int out_size, void* d_ws, size_t ws_size,
                              hipStream_t stream) {
    const float* x   = (const float*)d_in[0];
    const float* Wq  = (const float*)d_in[1];
    const float* Wk  = (const float*)d_in[2];
    const float* Wv  = (const float*)d_in[3];
    const float* Wfc = (const float*)d_in[4];

    // B=4, S=4096, DM=1024 -> M=16384, K=1024, Nqkv=3072
    const int M = 16384, K = 1024, NQKV = 3072, N2 = 1024;

    // ws: 72 MB. Q||K scratch lives in d_out (u16), overwritten by
    // GEMM2's final fp32 store after attn consumed it (stream-ordered).
    char* ws = (char*)d_ws;
    u16* xb    = (u16*)ws;                                  // 33,554,432 B (also O later)
    u16* wqkvb = (u16*)(ws + 33554432);                     //  6,291,456 B
    u16* wfcb  = (u16*)(ws + 33554432 + 6291456);           //  2,097,152 B
    u16* vbuf  = (u16*)(ws + 33554432 + 6291456 + 2097152); // 33,554,432 B
    u16* qkbuf = (u16*)d_out;                               // 64 MB scratch

    cast_all<<<20480, 256, 0, stream>>>(x, Wq, Wk, Wv, Wfc, xb, wqkvb, wfcb);

    // GEMM1: proven 128-tile structure (~102-105us, MfmaUtil ~46%)
    gemm_bt<128, 0><<<dim3(NQKV / BN, M / 128), 256, 0, stream>>>(
        xb, wqkvb, qkbuf, vbuf, M, NQKV, K);

    u16* Ob = xb;   // alias: GEMM1 was the last reader of xb
    attn_kernel<<<M / 4, 256, 0, stream>>>(qkbuf, vbuf, Ob);

    // GEMM2: deep-pipelined 256^2 (256 blocks, %8==0)
    gemm_bt8<1><<<256, 512, 0, stream>>>(Ob, wfcb, d_out, nullptr, M, N2, K);
}